// Round 1
// baseline (4029.135 us; speedup 1.0000x reference)
//
#include <hip/hip_runtime.h>
#include <stdint.h>

#define LAYERS 4
#define BATCH  32
#define SEQT   128
#define HID    1024
#define VOCAB  32000
#define GATES  4096

typedef __attribute__((ext_vector_type(8))) short short8;
typedef __attribute__((ext_vector_type(8))) __bf16 bf16x8;
typedef __attribute__((ext_vector_type(4))) float floatx4;

// ws layout (bytes)
#define WIH_OFF 0ul
#define WHH_OFF 33554432ul
#define CLS_OFF 67108864ul
#define X_OFF   132644864ul
#define RES_OFF 141033472ul
#define HB_OFF  174587904ul   // [2][L][B][H] bf16 (parity double-buffer)
#define CF_OFF  175636480ul   // [L][B][H] f32
// end: 176160768

#define LOGITS_N 131072000ul

__device__ __forceinline__ unsigned short f2bf(float f) {
  union { float f; unsigned u; } v; v.f = f;
  unsigned r = v.u + 0x7FFF + ((v.u >> 16) & 1);
  return (unsigned short)(r >> 16);
}
__device__ __forceinline__ float bf2f(unsigned short b) {
  union { unsigned u; float f; } v; v.u = ((unsigned)b) << 16;
  return v.f;
}

__device__ __forceinline__ floatx4 mfma16(short8 a, short8 b, floatx4 c) {
  return __builtin_amdgcn_mfma_f32_16x16x32_bf16(
      __builtin_bit_cast(bf16x8, a), __builtin_bit_cast(bf16x8, b), c, 0, 0, 0);
}

// ---------------- prep kernels ----------------

__global__ void k_convert(const float* __restrict__ wih, const float* __restrict__ whh,
                          const float* __restrict__ clsw,
                          unsigned short* __restrict__ oW, unsigned short* __restrict__ oH,
                          unsigned short* __restrict__ oC) {
  const long long NW = 16777216LL;   // L*4H*H
  const long long NC = 32768000LL;   // V*H
  const long long total4 = (NW * 2 + NC) >> 2;
  for (long long i = (long long)blockIdx.x * blockDim.x + threadIdx.x; i < total4;
       i += (long long)gridDim.x * blockDim.x) {
    long long e = i << 2;
    const float* src; unsigned short* dst; long long off;
    if (e < NW)          { src = wih;  dst = oW; off = e; }
    else if (e < 2 * NW) { src = whh;  dst = oH; off = e - NW; }
    else                 { src = clsw; dst = oC; off = e - 2 * NW; }
    float4 v = *(const float4*)(src + off);
    ushort4 o; o.x = f2bf(v.x); o.y = f2bf(v.y); o.z = f2bf(v.z); o.w = f2bf(v.w);
    *(ushort4*)(dst + off) = o;
  }
}

__global__ void k_embed(const int* __restrict__ tok, const float* __restrict__ emb,
                        unsigned short* __restrict__ X) {
  const int bt = blockIdx.x;            // t*32 + b
  const int t = bt >> 5, b = bt & 31;
  const int v = tok[b * SEQT + t];      // dec_input is [B,T]
  const float4* src = (const float4*)(emb + (size_t)v * HID);
  ushort4* dst = (ushort4*)(X + (size_t)bt * HID);
  const int i = threadIdx.x;            // 256 threads * 4 floats = 1024
  float4 f = src[i];
  ushort4 o; o.x = f2bf(f.x); o.y = f2bf(f.y); o.z = f2bf(f.z); o.w = f2bf(f.w);
  dst[i] = o;
}

__global__ void k_init(const float* __restrict__ h0, const float* __restrict__ c0,
                       unsigned short* __restrict__ HB, float* __restrict__ CF) {
  const int i = blockIdx.x * blockDim.x + threadIdx.x;
  if (i < LAYERS * BATCH * HID) {
    HB[i] = f2bf(h0[i]);   // parity 0
    CF[i] = c0[i];
  }
}

// ---------------- pipelined LSTM stage ----------------
// stage s: layer l processes timestep t = s - l (if in range).
// 64 wgs per layer (16 hidden units each), 4 waves = 4 gates.

__global__ __launch_bounds__(256, 1) void k_stage(
    const unsigned short* __restrict__ Wih, const unsigned short* __restrict__ Whh,
    const float* __restrict__ bih, const float* __restrict__ bhh,
    const unsigned short* __restrict__ X, unsigned short* __restrict__ RES,
    unsigned short* __restrict__ HB, float* __restrict__ CF,
    float* __restrict__ out, int s) {
  const int l = blockIdx.x >> 6;
  const int t = s - l;
  if (t < 0 || t >= SEQT) return;
  const int widx = blockIdx.x & 63;
  const int j0 = widx << 4;
  const int tid = threadIdx.x;
  const int w = tid >> 6, lane = tid & 63, lo = lane & 15, hi = lane >> 4;

  const unsigned short* A0 = (l == 0)
      ? (X + (size_t)t * (BATCH * HID))
      : (RES + ((size_t)(l - 1) * SEQT + t) * (BATCH * HID));
  const unsigned short* A1 = HB + ((size_t)(t & 1) * LAYERS + l) * (BATCH * HID);

  const size_t brow = (size_t)l * GATES + (size_t)w * HID + j0 + lo;
  const unsigned short* B0 = Wih + brow * HID + hi * 8;
  const unsigned short* B1 = Whh + brow * HID + hi * 8;

  floatx4 acc0 = {0.f, 0.f, 0.f, 0.f};
  floatx4 acc1 = {0.f, 0.f, 0.f, 0.f};

  {   // x @ W_ih^T
    const unsigned short* a0 = A0 + (size_t)lo * HID + hi * 8;
    const unsigned short* a1 = A0 + (size_t)(lo + 16) * HID + hi * 8;
#pragma unroll 8
    for (int kk = 0; kk < 32; ++kk) {
      short8 av0 = *(const short8*)(a0 + kk * 32);
      short8 av1 = *(const short8*)(a1 + kk * 32);
      short8 bv  = *(const short8*)(B0 + kk * 32);
      acc0 = mfma16(av0, bv, acc0);
      acc1 = mfma16(av1, bv, acc1);
    }
  }
  {   // h @ W_hh^T
    const unsigned short* a0 = A1 + (size_t)lo * HID + hi * 8;
    const unsigned short* a1 = A1 + (size_t)(lo + 16) * HID + hi * 8;
#pragma unroll 8
    for (int kk = 0; kk < 32; ++kk) {
      short8 av0 = *(const short8*)(a0 + kk * 32);
      short8 av1 = *(const short8*)(a1 + kk * 32);
      short8 bv  = *(const short8*)(B1 + kk * 32);
      acc0 = mfma16(av0, bv, acc0);
      acc1 = mfma16(av1, bv, acc1);
    }
  }

  const float bias = bih[brow] + bhh[brow];

  __shared__ float glds[4][BATCH][16];
#pragma unroll
  for (int r = 0; r < 4; ++r) {
    glds[w][hi * 4 + r][lo]      = acc0[r] + bias;   // C: col=lane&15, row=(lane>>4)*4+r
    glds[w][16 + hi * 4 + r][lo] = acc1[r] + bias;
  }
  __syncthreads();

  unsigned short* HBw = HB + ((size_t)((t + 1) & 1) * LAYERS + l) * (BATCH * HID);
  unsigned short* RESw = RES + ((size_t)l * SEQT + t) * (BATCH * HID);

#pragma unroll
  for (int e = tid; e < BATCH * 16; e += 256) {
    const int b = e >> 4, u = e & 15;
    const float ig = glds[0][b][u];
    const float fg = glds[1][b][u];
    const float gg = glds[2][b][u];
    const float og = glds[3][b][u];
    const float si = 1.f / (1.f + __expf(-ig));
    const float sf = 1.f / (1.f + __expf(-fg));
    const float so = 1.f / (1.f + __expf(-og));
    const float tg = tanhf(gg);
    const size_t cidx = (size_t)l * (BATCH * HID) + (size_t)b * HID + j0 + u;
    const float cn = sf * CF[cidx] + si * tg;
    const float hn = so * tanhf(cn);
    CF[cidx] = cn;
    HBw[(size_t)b * HID + j0 + u] = f2bf(hn);
    const float inp = bf2f(A0[(size_t)b * HID + j0 + u]);
    RESw[(size_t)b * HID + j0 + u] = f2bf(hn + inp);
    if (t == SEQT - 1) {
      out[LOGITS_N + cidx] = hn;                 // hT
      out[LOGITS_N + 131072ul + cidx] = cn;      // cT
    }
  }
}

// ---------------- classifier GEMM ----------------
// C[b*T+t][v] = resid3[t*32+b][:] . cls_W[v][:] + cls_b[v]
// 128x128 tile, BK=64, 4 waves of 64x64, XOR-swizzled LDS.

__global__ __launch_bounds__(256, 2) void k_cls(
    const unsigned short* __restrict__ A, const unsigned short* __restrict__ Bw,
    const float* __restrict__ bias, float* __restrict__ out) {
  __shared__ unsigned short lA[128 * 64];
  __shared__ unsigned short lB[128 * 64];
  const int ntile = blockIdx.x >> 5;      // 0..249
  const int mtile = blockIdx.x & 31;      // 0..31 (consecutive blocks share B-strip)
  const int m0 = mtile << 7, n0 = ntile << 7;
  const int tid = threadIdx.x;
  const int w = tid >> 6, lane = tid & 63, lo = lane & 15, hi = lane >> 4;
  const int mw = (w >> 1) << 6, nw = (w & 1) << 6;

  floatx4 acc[4][4];
#pragma unroll
  for (int i = 0; i < 4; ++i)
#pragma unroll
    for (int j = 0; j < 4; ++j) acc[i][j] = {0.f, 0.f, 0.f, 0.f};

  for (int k0 = 0; k0 < HID; k0 += 64) {
#pragma unroll
    for (int q = 0; q < 4; ++q) {
      const int e = q * 256 + tid;        // 0..1023 (16B chunks)
      const int row = e >> 3, c8 = e & 7;
      const int ps = row * 64 + ((c8 ^ (row & 7)) << 3);   // swizzled (shorts)
      *(short8*)(lA + ps) = *(const short8*)(A  + (size_t)(m0 + row) * HID + k0 + (c8 << 3));
      *(short8*)(lB + ps) = *(const short8*)(Bw + (size_t)(n0 + row) * HID + k0 + (c8 << 3));
    }
    __syncthreads();
#pragma unroll
    for (int kk = 0; kk < 2; ++kk) {
      short8 af[4], bfr[4];
#pragma unroll
      for (int x = 0; x < 4; ++x) {
        const int ra = mw + x * 16 + lo;
        af[x]  = *(const short8*)(lA + ra * 64 + ((((kk << 2) + hi) ^ (ra & 7)) << 3));
        const int rb = nw + x * 16 + lo;
        bfr[x] = *(const short8*)(lB + rb * 64 + ((((kk << 2) + hi) ^ (rb & 7)) << 3));
      }
#pragma unroll
      for (int mi = 0; mi < 4; ++mi)
#pragma unroll
        for (int ni = 0; ni < 4; ++ni)
          acc[mi][ni] = mfma16(af[mi], bfr[ni], acc[mi][ni]);
    }
    __syncthreads();
  }

#pragma unroll
  for (int mi = 0; mi < 4; ++mi) {
#pragma unroll
    for (int ni = 0; ni < 4; ++ni) {
      const int v = n0 + nw + ni * 16 + lo;
      const float bv = bias[v];
#pragma unroll
      for (int r = 0; r < 4; ++r) {
        const int ra = m0 + mw + mi * 16 + hi * 4 + r;       // A row = t*32+b
        const int orow = (ra & 31) * SEQT + (ra >> 5);       // out row = b*128+t
        out[(size_t)orow * VOCAB + v] = acc[mi][ni][r] + bv;
      }
    }
  }
}

// ---------------- launch ----------------

extern "C" void kernel_launch(void* const* d_in, const int* in_sizes, int n_in,
                              void* d_out, int out_size, void* d_ws, size_t ws_size,
                              hipStream_t stream) {
  (void)in_sizes; (void)n_in; (void)out_size; (void)ws_size;
  const int*   tok  = (const int*)d_in[0];
  const float* h0   = (const float*)d_in[1];
  const float* c0   = (const float*)d_in[2];
  const float* emb  = (const float*)d_in[3];
  const float* wih  = (const float*)d_in[4];
  const float* whh  = (const float*)d_in[5];
  const float* bih  = (const float*)d_in[6];
  const float* bhh  = (const float*)d_in[7];
  const float* clsw = (const float*)d_in[8];
  const float* clsb = (const float*)d_in[9];
  float* out = (float*)d_out;
  char* ws = (char*)d_ws;

  unsigned short* Wih = (unsigned short*)(ws + WIH_OFF);
  unsigned short* Whh = (unsigned short*)(ws + WHH_OFF);
  unsigned short* Cls = (unsigned short*)(ws + CLS_OFF);
  unsigned short* X   = (unsigned short*)(ws + X_OFF);
  unsigned short* RES = (unsigned short*)(ws + RES_OFF);
  unsigned short* HB  = (unsigned short*)(ws + HB_OFF);
  float*          CF  = (float*)(ws + CF_OFF);

  hipLaunchKernelGGL(k_convert, dim3(4096), dim3(256), 0, stream, wih, whh, clsw, Wih, Whh, Cls);
  hipLaunchKernelGGL(k_embed,   dim3(SEQT * BATCH), dim3(256), 0, stream, tok, emb, X);
  hipLaunchKernelGGL(k_init,    dim3(512), dim3(256), 0, stream, h0, c0, HB, CF);

  for (int s = 0; s < SEQT + LAYERS - 1; ++s)
    hipLaunchKernelGGL(k_stage, dim3(256), dim3(256), 0, stream,
                       Wih, Whh, bih, bhh, X, RES, HB, CF, out, s);

  hipLaunchKernelGGL(k_cls, dim3(250 * 32), dim3(256), 0, stream,
                     RES + (size_t)3 * SEQT * BATCH * HID, Cls, clsb, out);
}